// Round 17
// baseline (318.185 us; speedup 1.0000x reference)
//
#include <hip/hip_runtime.h>
#include <stdint.h>

// GraphSAGE: 3x SAGEConv(mean) + global_mean_pool + fixed-key dropout + linear.
// N=50000, E=800000, D_IN=128, D_H=128, G=64. d_out = 1088 f32.
// Round-17: consolidation — single-kernel scan (a+b+c merged), k_final fused
// into k_pool, agg2 stored/read as bf16. 12 kernels total.
// Mask: JAX partitionable threefry (bits=o0^o1, x=(0,i), keep iff MSB==0).

#define GG 64
#define NXCD 8
#define BCAP 112000

typedef __attribute__((ext_vector_type(8))) unsigned short ushort8;
typedef __attribute__((ext_vector_type(8))) short bf16s8;
typedef __attribute__((ext_vector_type(4))) float f32x4;

__device__ __forceinline__ unsigned short rne_bf16(float f) {
  unsigned u = __float_as_uint(f);
  return (unsigned short)((u + 0x7FFFu + ((u >> 16) & 1u)) >> 16);
}
__device__ __forceinline__ float bf2f(unsigned short b) {
  return __uint_as_float(((unsigned)b) << 16);
}

// ---------------- fused x->bf16 + weight prep + deg/bcur zeroing ----------------
__global__ __launch_bounds__(256) void k_cvtprep(const float* __restrict__ x, unsigned short* __restrict__ xb,
                                                 int n8, int N,
                                                 const float* __restrict__ Wl1, const float* __restrict__ Wr1,
                                                 const float* __restrict__ Wl2, const float* __restrict__ Wr2,
                                                 const float* __restrict__ Wl3, const float* __restrict__ Wr3,
                                                 unsigned short* __restrict__ WT1l, unsigned short* __restrict__ WT1r,
                                                 unsigned short* __restrict__ WT2l, unsigned short* __restrict__ WT2r,
                                                 unsigned short* __restrict__ wc3b,
                                                 int* __restrict__ deg, int* __restrict__ bcur) {
  int idx = blockIdx.x * 256 + threadIdx.x;
  if (idx < n8) {
    const float4* p = (const float4*)(x + (size_t)idx * 8);
    float4 v0 = p[0], v1 = p[1];
    ushort8 o;
    o[0] = rne_bf16(v0.x); o[1] = rne_bf16(v0.y); o[2] = rne_bf16(v0.z); o[3] = rne_bf16(v0.w);
    o[4] = rne_bf16(v1.x); o[5] = rne_bf16(v1.y); o[6] = rne_bf16(v1.z); o[7] = rne_bf16(v1.w);
    *(ushort8*)(xb + (size_t)idx * 8) = o;
    return;
  }
  int j = idx - n8;
  if (j < 32768) {
    int k = j >> 8, m = j & 255;
    WT1l[m * 128 + k] = rne_bf16(Wl1[j]);
    WT1r[m * 128 + k] = rne_bf16(Wr1[j]);
  } else if (j < 65536) {
    int q = j - 32768;
    int k = q >> 7, m = q & 127;
    WT2l[m * 256 + k] = rne_bf16(Wl2[q]);
    WT2r[m * 256 + k] = rne_bf16(Wr2[q]);
  } else if (j < 69632) {
    int q = j - 65536;            // q = m*128 + k
    int m = q >> 7, k = q & 127;
    float v = (m < 16) ? Wl3[k * 16 + m] : Wr3[k * 16 + (m - 16)];
    wc3b[q] = rne_bf16(v);
  } else if (j < 69632 + N) {
    deg[j - 69632] = 0;
  } else if (j < 69632 + N + NXCD) {
    bcur[j - 69632 - N] = 0;
  }
}

// ---------------- bucket pass: deg atomics + dst-slice partition ----------------
__global__ __launch_bounds__(256) void k_bucket(const int* __restrict__ src, const int* __restrict__ dst,
                                                int* __restrict__ deg, int* __restrict__ bcur,
                                                int2* __restrict__ bucket, int E, int binsz) {
  __shared__ int cnt[NXCD];
  __shared__ int base[NXCD];
  const int tid = threadIdx.x;
  if (tid < NXCD) cnt[tid] = 0;
  __syncthreads();
  int e0 = (blockIdx.x * 256 + tid) * 4;
  int d[4], s[4], bk[4], rk[4];
  int nv = 0;
  if (e0 + 3 < E) {
    int4 d4 = *(const int4*)(dst + e0);
    int4 s4 = *(const int4*)(src + e0);
    d[0] = d4.x; d[1] = d4.y; d[2] = d4.z; d[3] = d4.w;
    s[0] = s4.x; s[1] = s4.y; s[2] = s4.z; s[3] = s4.w;
    nv = 4;
  } else {
    for (int e = e0; e < E && nv < 4; ++e) { d[nv] = dst[e]; s[nv] = src[e]; ++nv; }
  }
#pragma unroll
  for (int k = 0; k < 4; ++k)
    if (k < nv) {
      atomicAdd(&deg[d[k]], 1);
      bk[k] = d[k] / binsz;
      rk[k] = atomicAdd(&cnt[bk[k]], 1);
    }
  __syncthreads();
  if (tid < NXCD) base[tid] = atomicAdd(&bcur[tid], cnt[tid]);
  __syncthreads();
#pragma unroll
  for (int k = 0; k < 4; ++k)
    if (k < nv) {
      int p = min(base[bk[k]] + rk[k], BCAP - 1);
      bucket[(size_t)bk[k] * BCAP + p] = make_int2(s[k], d[k]);
    }
}

// ---------------- single-kernel scan (1 block, 1024 thr): off = exscan(deg), cur = off ----------------
__global__ __launch_bounds__(1024) void k_scan(const int* __restrict__ deg, int* __restrict__ off,
                                               int* __restrict__ cur, int N) {
  __shared__ int sm[1024];
  const int tid = threadIdx.x;
  int running = 0;
  for (int base = 0; base < N; base += 1024) {
    int i = base + tid;
    int v = (i < N) ? deg[i] : 0;
    sm[tid] = v;
    __syncthreads();
    for (int d = 1; d < 1024; d <<= 1) {
      int t = (tid >= d) ? sm[tid - d] : 0;
      __syncthreads();
      sm[tid] += t;
      __syncthreads();
    }
    if (i < N) {
      int o = running + sm[tid] - v;
      off[i] = o;
      cur[i] = o;
    }
    int ct = sm[1023];
    __syncthreads();
    running += ct;
  }
  if (tid == 0) off[N] = running;
}

// ---------------- per-XCD fill from own bucket (L2-local stores) ----------------
__global__ __launch_bounds__(256) void k_fill2(const int2* __restrict__ bucket, const int* __restrict__ bcnt,
                                               const int* __restrict__ off, int* __restrict__ cur,
                                               int* __restrict__ eidx, int N, int binsz, int ngrp) {
  const int xcd = blockIdx.x & (NXCD - 1);
  const int grp = blockIdx.x >> 3;
  const int t = grp * 256 + threadIdx.x;
  const int nthr = ngrp * 256;
  const int lo = xcd * binsz;
  const int hi = min(lo + binsz, N);

  int s0 = off[lo] & ~15;
  int s1 = off[hi];
  for (int i = s0 + t * 16; i < s1; i += nthr * 16) {
    int v = eidx[i];
    asm volatile("" :: "v"(v));
  }

  const int cnt = min(bcnt[xcd], BCAP);
  const int2* seg = bucket + (size_t)xcd * BCAP;
  for (int e = t; e < cnt; e += nthr) {
    int2 sd = seg[e];
    int p = atomicAdd(&cur[sd.y], 1);
    eidx[p] = sd.x;
  }
}

// ---------------- gather-mean, bf16 input (D=128), bf16 out, 4-way unrolled ----------------
__global__ __launch_bounds__(256) void k_aggr_b(const unsigned short* __restrict__ feat,
                                                const int* __restrict__ off, const int* __restrict__ eidx,
                                                unsigned short* __restrict__ out, int N) {
  int idx = blockIdx.x * 256 + threadIdx.x;
  int n = idx >> 4;
  if (n >= N) return;
  int c = (idx & 15) * 8;
  int b = off[n], e = off[n + 1];
  float s0 = 0.f, s1 = 0.f, s2 = 0.f, s3 = 0.f, s4 = 0.f, s5 = 0.f, s6 = 0.f, s7 = 0.f;
  int j = b;
  for (; j + 3 < e; j += 4) {
    int i0 = eidx[j], i1 = eidx[j + 1], i2 = eidx[j + 2], i3 = eidx[j + 3];
    ushort8 v0 = *(const ushort8*)&feat[(size_t)i0 * 128 + c];
    ushort8 v1 = *(const ushort8*)&feat[(size_t)i1 * 128 + c];
    ushort8 v2 = *(const ushort8*)&feat[(size_t)i2 * 128 + c];
    ushort8 v3 = *(const ushort8*)&feat[(size_t)i3 * 128 + c];
    s0 += bf2f(v0[0]) + bf2f(v1[0]) + bf2f(v2[0]) + bf2f(v3[0]);
    s1 += bf2f(v0[1]) + bf2f(v1[1]) + bf2f(v2[1]) + bf2f(v3[1]);
    s2 += bf2f(v0[2]) + bf2f(v1[2]) + bf2f(v2[2]) + bf2f(v3[2]);
    s3 += bf2f(v0[3]) + bf2f(v1[3]) + bf2f(v2[3]) + bf2f(v3[3]);
    s4 += bf2f(v0[4]) + bf2f(v1[4]) + bf2f(v2[4]) + bf2f(v3[4]);
    s5 += bf2f(v0[5]) + bf2f(v1[5]) + bf2f(v2[5]) + bf2f(v3[5]);
    s6 += bf2f(v0[6]) + bf2f(v1[6]) + bf2f(v2[6]) + bf2f(v3[6]);
    s7 += bf2f(v0[7]) + bf2f(v1[7]) + bf2f(v2[7]) + bf2f(v3[7]);
  }
  for (; j < e; ++j) {
    int sidx = eidx[j];
    ushort8 v = *(const ushort8*)&feat[(size_t)sidx * 128 + c];
    s0 += bf2f(v[0]); s1 += bf2f(v[1]); s2 += bf2f(v[2]); s3 += bf2f(v[3]);
    s4 += bf2f(v[4]); s5 += bf2f(v[5]); s6 += bf2f(v[6]); s7 += bf2f(v[7]);
  }
  float sc = 1.f / fmaxf((float)(e - b), 1.f);
  ushort8 o;
  o[0] = rne_bf16(s0 * sc); o[1] = rne_bf16(s1 * sc); o[2] = rne_bf16(s2 * sc); o[3] = rne_bf16(s3 * sc);
  o[4] = rne_bf16(s4 * sc); o[5] = rne_bf16(s5 * sc); o[6] = rne_bf16(s6 * sc); o[7] = rne_bf16(s7 * sc);
  *(ushort8*)&out[(size_t)n * 128 + c] = o;
}

// ---------------- bf16 MFMA GEMM 64x64 tile; C0 (residual) read as bf16 ----------------
template <int DUAL, int HAS_C0, int HAS_BIAS, int RELU, int OUT_BF16>
__global__ __launch_bounds__(256) void k_mgemm(
    const unsigned short* __restrict__ A1, int K1, const unsigned short* __restrict__ B1,
    const unsigned short* __restrict__ A2, const unsigned short* __restrict__ B2, int K2,
    const unsigned short* __restrict__ C0, const float* __restrict__ bias,
    void* __restrict__ Cout, int N, int M) {
  __shared__ unsigned short As[64 * 32];
  __shared__ unsigned short Bs[64 * 32];
  const int tid = threadIdx.x;
  const int row0 = blockIdx.y * 64;
  const int col0 = blockIdx.x * 64;
  const int lane = tid & 63;
  const int w = tid >> 6;
  const int wr = w >> 1, wc = w & 1;
  const int rl = lane & 15, g = lane >> 4;
  const int pos = ((g ^ ((rl >> 1) & 3)) << 3);
  const int srow = tid >> 2;
  const int schunk = tid & 3;
  const int spos = ((schunk ^ ((srow >> 1) & 3)) << 3);

  f32x4 acc00 = {0.f, 0.f, 0.f, 0.f}, acc01 = acc00, acc10 = acc00, acc11 = acc00;

  for (int pass = 0; pass < (DUAL ? 2 : 1); ++pass) {
    const unsigned short* __restrict__ A = pass ? A2 : A1;
    const unsigned short* __restrict__ B = pass ? B2 : B1;
    const int K = pass ? K2 : K1;
    for (int k0 = 0; k0 < K; k0 += 32) {
      {
        int r = row0 + srow;
        ushort8 va = (ushort8)(0);
        if (r < N) va = *(const ushort8*)&A[(size_t)r * K + k0 + schunk * 8];
        *(ushort8*)&As[srow * 32 + spos] = va;
        ushort8 vb = *(const ushort8*)&B[(size_t)(col0 + srow) * K + k0 + schunk * 8];
        *(ushort8*)&Bs[srow * 32 + spos] = vb;
      }
      __syncthreads();
      bf16s8 a0 = *(bf16s8*)&As[(wr * 32 + rl) * 32 + pos];
      bf16s8 a1 = *(bf16s8*)&As[(wr * 32 + 16 + rl) * 32 + pos];
      bf16s8 b0 = *(bf16s8*)&Bs[(wc * 32 + rl) * 32 + pos];
      bf16s8 b1 = *(bf16s8*)&Bs[(wc * 32 + 16 + rl) * 32 + pos];
      acc00 = __builtin_amdgcn_mfma_f32_16x16x32_bf16(a0, b0, acc00, 0, 0, 0);
      acc01 = __builtin_amdgcn_mfma_f32_16x16x32_bf16(a0, b1, acc01, 0, 0, 0);
      acc10 = __builtin_amdgcn_mfma_f32_16x16x32_bf16(a1, b0, acc10, 0, 0, 0);
      acc11 = __builtin_amdgcn_mfma_f32_16x16x32_bf16(a1, b1, acc11, 0, 0, 0);
      __syncthreads();
    }
  }

#pragma unroll
  for (int fi = 0; fi < 2; ++fi)
#pragma unroll
    for (int fj = 0; fj < 2; ++fj) {
      const f32x4 a = fi ? (fj ? acc11 : acc10) : (fj ? acc01 : acc00);
#pragma unroll
      for (int reg = 0; reg < 4; ++reg) {
        int r = row0 + wr * 32 + fi * 16 + g * 4 + reg;
        int c = col0 + wc * 32 + fj * 16 + rl;
        if (r >= N) continue;
        float v = a[reg];
        if (HAS_C0) v += bf2f(C0[(size_t)r * M + c]);
        if (HAS_BIAS) v += bias[c];
        if (RELU) v = fmaxf(v, 0.f);
        if (OUT_BF16) ((unsigned short*)Cout)[(size_t)r * M + c] = rne_bf16(v);
        else ((float*)Cout)[(size_t)r * M + c] = v;
      }
    }
}

// ---------------- layer-3 MFMA GEMM: 128x32 tile, K=128 ----------------
__global__ __launch_bounds__(256) void k_mgemm3(const unsigned short* __restrict__ A,
                                                const unsigned short* __restrict__ B,
                                                float* __restrict__ C, int N) {
  __shared__ unsigned short As[128 * 32];
  __shared__ unsigned short Bs[32 * 32];
  const int tid = threadIdx.x;
  const int row0 = blockIdx.x * 128;
  const int lane = tid & 63;
  const int w = tid >> 6;
  const int rl = lane & 15, g = lane >> 4;
  const int pos = ((g ^ ((rl >> 1) & 3)) << 3);

  f32x4 acc00 = {0.f, 0.f, 0.f, 0.f}, acc01 = acc00, acc10 = acc00, acc11 = acc00;

  for (int k0 = 0; k0 < 128; k0 += 32) {
#pragma unroll
    for (int it = 0; it < 2; ++it) {
      int cid = tid + it * 256;
      int row = cid >> 2, ch = cid & 3;
      int r = row0 + row;
      ushort8 va = (ushort8)(0);
      if (r < N) va = *(const ushort8*)&A[(size_t)r * 128 + k0 + ch * 8];
      *(ushort8*)&As[row * 32 + ((ch ^ ((row >> 1) & 3)) << 3)] = va;
    }
    if (tid < 128) {
      int row = tid >> 2, ch = tid & 3;
      ushort8 vb = *(const ushort8*)&B[(size_t)row * 128 + k0 + ch * 8];
      *(ushort8*)&Bs[row * 32 + ((ch ^ ((row >> 1) & 3)) << 3)] = vb;
    }
    __syncthreads();
    bf16s8 a0 = *(bf16s8*)&As[(w * 32 + rl) * 32 + pos];
    bf16s8 a1 = *(bf16s8*)&As[(w * 32 + 16 + rl) * 32 + pos];
    bf16s8 b0 = *(bf16s8*)&Bs[rl * 32 + pos];
    bf16s8 b1 = *(bf16s8*)&Bs[(16 + rl) * 32 + pos];
    acc00 = __builtin_amdgcn_mfma_f32_16x16x32_bf16(a0, b0, acc00, 0, 0, 0);
    acc01 = __builtin_amdgcn_mfma_f32_16x16x32_bf16(a0, b1, acc01, 0, 0, 0);
    acc10 = __builtin_amdgcn_mfma_f32_16x16x32_bf16(a1, b0, acc10, 0, 0, 0);
    acc11 = __builtin_amdgcn_mfma_f32_16x16x32_bf16(a1, b1, acc11, 0, 0, 0);
    __syncthreads();
  }

#pragma unroll
  for (int fi = 0; fi < 2; ++fi)
#pragma unroll
    for (int fj = 0; fj < 2; ++fj) {
      const f32x4 a = fi ? (fj ? acc11 : acc10) : (fj ? acc01 : acc00);
#pragma unroll
      for (int reg = 0; reg < 4; ++reg) {
        int r = row0 + w * 32 + fi * 16 + g * 4 + reg;
        int c = fj * 16 + rl;
        if (r < N) C[(size_t)r * 32 + c] = a[reg];
      }
    }
}

// ---------------- fused layer-3 aggregate + combine (4-way unrolled) ----------------
__global__ __launch_bounds__(256) void k_l3post(const float* __restrict__ g3, const int* __restrict__ off,
                                                const int* __restrict__ eidx, const float* __restrict__ bl3,
                                                float* __restrict__ h3, int N) {
  int idx = blockIdx.x * 256 + threadIdx.x;
  int n = idx >> 2;
  if (n >= N) return;
  int c = (idx & 3) << 2;
  int b = off[n], e = off[n + 1];
  float ax = 0.f, ay = 0.f, az = 0.f, aw = 0.f;
  int j = b;
  for (; j + 3 < e; j += 4) {
    int i0 = eidx[j], i1 = eidx[j + 1], i2 = eidx[j + 2], i3 = eidx[j + 3];
    const float4 v0 = *(const float4*)&g3[(size_t)i0 * 32 + c];
    const float4 v1 = *(const float4*)&g3[(size_t)i1 * 32 + c];
    const float4 v2 = *(const float4*)&g3[(size_t)i2 * 32 + c];
    const float4 v3 = *(const float4*)&g3[(size_t)i3 * 32 + c];
    ax += v0.x + v1.x + v2.x + v3.x;
    ay += v0.y + v1.y + v2.y + v3.y;
    az += v0.z + v1.z + v2.z + v3.z;
    aw += v0.w + v1.w + v2.w + v3.w;
  }
  for (; j < e; ++j) {
    int s = eidx[j];
    const float4 v = *(const float4*)&g3[(size_t)s * 32 + c];
    ax += v.x; ay += v.y; az += v.z; aw += v.w;
  }
  float sc = 1.f / fmaxf((float)(e - b), 1.f);
  const float4 r2 = *(const float4*)&g3[(size_t)n * 32 + 16 + c];
  const float4 bb = *(const float4*)&bl3[c];
  *(float4*)&h3[(size_t)n * 16 + c] =
      make_float4(ax * sc + r2.x + bb.x, ay * sc + r2.y + bb.y,
                  az * sc + r2.z + bb.z, aw * sc + r2.w + bb.w);
}

// ---------------- threefry2x32 ----------------
__device__ __forceinline__ uint2 tf2x32(unsigned k0, unsigned k1, unsigned x0, unsigned x1) {
  const unsigned ks[3] = {k0, k1, k0 ^ k1 ^ 0x1BD11BDAu};
  const int rotA[4] = {13, 15, 26, 6}, rotB[4] = {17, 29, 16, 24};
  x0 += ks[0];
  x1 += ks[1];
#pragma unroll
  for (int i = 0; i < 5; ++i) {
    const int* R = (i & 1) ? rotB : rotA;
#pragma unroll
    for (int j = 0; j < 4; ++j) {
      x0 += x1;
      x1 = (x1 << R[j]) | (x1 >> (32 - R[j]));
      x1 ^= x0;
    }
    x0 += ks[(i + 1) % 3];
    x1 += ks[(i + 2) % 3] + (unsigned)(i + 1);
  }
  return make_uint2(x0, x1);
}

// ---------------- global mean pool + dropout + final linear (fused) ----------------
__device__ __forceinline__ int lbound(const int* __restrict__ a, int n, int v) {
  int lo = 0, hi = n;
  while (lo < hi) {
    int mid = (lo + hi) >> 1;
    if (a[mid] < v) lo = mid + 1; else hi = mid;
  }
  return lo;
}

__global__ __launch_bounds__(256) void k_poolfinal(const float* __restrict__ h3, const int* __restrict__ batch,
                                                   int N, const float* __restrict__ Wc,
                                                   const float* __restrict__ bc, float* __restrict__ outp) {
  __shared__ float sm[4][16];
  int g = blockIdx.x, tid = threadIdx.x;
  int start = lbound(batch, N, g);
  int end = lbound(batch, N, g + 1);
  float acc[16];
#pragma unroll
  for (int j = 0; j < 16; ++j) acc[j] = 0.f;
  for (int i = start + tid; i < end; i += 256) {
    const float4* p = (const float4*)&h3[(size_t)i * 16];
    float4 v0 = p[0], v1 = p[1], v2 = p[2], v3 = p[3];
    acc[0] += v0.x; acc[1] += v0.y; acc[2] += v0.z; acc[3] += v0.w;
    acc[4] += v1.x; acc[5] += v1.y; acc[6] += v1.z; acc[7] += v1.w;
    acc[8] += v2.x; acc[9] += v2.y; acc[10] += v2.z; acc[11] += v2.w;
    acc[12] += v3.x; acc[13] += v3.y; acc[14] += v3.z; acc[15] += v3.w;
  }
#pragma unroll
  for (int j = 0; j < 16; ++j) {
    float v = acc[j];
    v += __shfl_down(v, 32);
    v += __shfl_down(v, 16);
    v += __shfl_down(v, 8);
    v += __shfl_down(v, 4);
    v += __shfl_down(v, 2);
    v += __shfl_down(v, 1);
    if ((tid & 63) == 0) sm[tid >> 6][j] = v;
  }
  __syncthreads();
  if (tid < 16) {
    float v = sm[0][tid] + sm[1][tid] + sm[2][tid] + sm[3][tid];
    v /= fmaxf((float)(end - start), 1.f);
    outp[64 + g * 16 + tid] = v;                       // output 1 (h_pool)
    // fused dropout + linear: t = g*16 + tid
    uint2 r = tf2x32(0u, 42u, 0u, (unsigned)(g * 16 + tid));
    unsigned bits = r.x ^ r.y;
    float hd = (bits >> 31) ? 0.f : 2.f * v;
    float contrib = hd * Wc[tid];
    contrib += __shfl_down(contrib, 8, 16);
    contrib += __shfl_down(contrib, 4, 16);
    contrib += __shfl_down(contrib, 2, 16);
    contrib += __shfl_down(contrib, 1, 16);
    if (tid == 0) outp[g] = contrib + bc[0];           // output 0
  }
}

extern "C" void kernel_launch(void* const* d_in, const int* in_sizes, int n_in,
                              void* d_out, int out_size, void* d_ws, size_t ws_size,
                              hipStream_t stream) {
  const float* x   = (const float*)d_in[0];
  const int*   ei  = (const int*)d_in[1];
  const int*   bat = (const int*)d_in[2];
  const float* Wl1 = (const float*)d_in[3];
  const float* bl1 = (const float*)d_in[4];
  const float* Wr1 = (const float*)d_in[5];
  const float* Wl2 = (const float*)d_in[6];
  const float* bl2 = (const float*)d_in[7];
  const float* Wr2 = (const float*)d_in[8];
  const float* Wl3 = (const float*)d_in[9];
  const float* bl3 = (const float*)d_in[10];
  const float* Wr3 = (const float*)d_in[11];
  const float* Wc  = (const float*)d_in[12];
  const float* bc  = (const float*)d_in[13];

  const int E = in_sizes[1] / 2;   // 800000
  const int N = in_sizes[2];       // 50000
  const int* src = ei;
  const int* dst = ei + E;

  // workspace layout (4-byte words)
  int*   off   = (int*)d_ws;                          // [0, 50016)
  int*   deg   = off + 50016;                         // [50016, 100016)
  int*   bcur  = (int*)d_ws + 100080;                 // 8
  unsigned short* wc3b = (unsigned short*)((float*)d_ws + 101120);  // 32x128 bf16
  unsigned short* WT1l = (unsigned short*)((float*)d_ws + 105216);  // 256x128 bf16
  unsigned short* WT1r = (unsigned short*)((float*)d_ws + 121600);
  unsigned short* WT2l = (unsigned short*)((float*)d_ws + 137984);  // 128x256 bf16
  unsigned short* WT2r = (unsigned short*)((float*)d_ws + 154368);
  int*   eidx  = (int*)d_ws + 170752;                 // E
  unsigned short* xb   = (unsigned short*)((float*)d_ws + 970752);    // N*128 bf16
  unsigned short* aggb = (unsigned short*)((float*)d_ws + 4170752);   // N*128 bf16 (agg1 & agg2)
  unsigned short* h1b  = (unsigned short*)((float*)d_ws + 7370752);   // N*256 bf16
  unsigned short* t2b  = xb;                                          // alias (xb dead)
  unsigned short* h2b  = (unsigned short*)((float*)d_ws + 970752);    // N*128 bf16 (t2b dead)
  int*   cur  = (int*)((float*)d_ws + 13770752);      // N cursor
  int2*  bucket = (int2*)((float*)d_ws + 13820800);   // 8*BCAP int2 (dead before aggs reuse nothing here)
  float* g3   = (float*)d_ws + 7370752;               // N*32 f32 (h1b dead)
  float* h3   = (float*)d_ws + 8970752;               // N*16 f32
  float* outp = (float*)d_out;                        // 1088 f32

  const int gy = (N + 63) / 64;                       // 782
  const int gy3 = (N + 127) / 128;                    // 391
  const int n8 = N * 128 / 8;                         // 800000
  const int binsz = (N + NXCD - 1) / NXCD;            // 6250
  const int ngrp = 64;

  // prep: x->bf16 + weights + deg/bcur zeroing
  const int prep_total = n8 + 69632 + N + NXCD;
  k_cvtprep<<<(prep_total + 255) / 256, 256, 0, stream>>>(x, xb, n8, N, Wl1, Wr1, Wl2, Wr2, Wl3, Wr3,
                                                          WT1l, WT1r, WT2l, WT2r, wc3b, deg, bcur);

  // CSR build: bucket -> scan (single kernel) -> fill2
  k_bucket<<<((E + 3) / 4 + 255) / 256, 256, 0, stream>>>(src, dst, deg, bcur, bucket, E, binsz);
  k_scan<<<1, 1024, 0, stream>>>(deg, off, cur, N);
  k_fill2<<<ngrp * NXCD, 256, 0, stream>>>(bucket, bcur, off, cur, eidx, N, binsz, ngrp);

  // layer 1
  k_aggr_b<<<(N * 16 + 255) / 256, 256, 0, stream>>>(xb, off, eidx, aggb, N);
  k_mgemm<1, 0, 1, 1, 1><<<dim3(4, gy), 256, 0, stream>>>(aggb, 128, WT1l, xb, WT1r, 128,
                                                          nullptr, bl1, h1b, N, 256);

  // layer 2 (agg2 reuses aggb region, bf16)
  k_mgemm<0, 0, 0, 0, 1><<<dim3(2, gy), 256, 0, stream>>>(h1b, 256, WT2l, nullptr, nullptr, 0,
                                                          nullptr, nullptr, t2b, N, 128);
  k_aggr_b<<<(N * 16 + 255) / 256, 256, 0, stream>>>(t2b, off, eidx, aggb, N);
  k_mgemm<0, 1, 1, 1, 1><<<dim3(2, gy), 256, 0, stream>>>(h1b, 256, WT2r, nullptr, nullptr, 0,
                                                          aggb, bl2, h2b, N, 128);

  // layer 3
  k_mgemm3<<<gy3, 256, 0, stream>>>(h2b, wc3b, g3, N);
  k_l3post<<<(N * 4 + 255) / 256, 256, 0, stream>>>(g3, off, eidx, bl3, h3, N);

  // pool + dropout + final linear (fused)
  k_poolfinal<<<GG, 256, 0, stream>>>(h3, bat, N, Wc, bc, outp);
}

// Round 18
// 238.549 us; speedup vs baseline: 1.3338x; 1.3338x over previous
//
#include <hip/hip_runtime.h>
#include <stdint.h>

// GraphSAGE: 3x SAGEConv(mean) + global_mean_pool + fixed-key dropout + linear.
// N=50000, E=800000, D_IN=128, D_H=128, G=64. d_out = 1088 f32.
// Round-18: revert single-block scan (89us!) to 3-phase parallel scan; keep
// fused pool+final and bf16 agg2 from round-17.
// Mask: JAX partitionable threefry (bits=o0^o1, x=(0,i), keep iff MSB==0).

#define GG 64
#define NXCD 8
#define BCAP 112000

typedef __attribute__((ext_vector_type(8))) unsigned short ushort8;
typedef __attribute__((ext_vector_type(8))) short bf16s8;
typedef __attribute__((ext_vector_type(4))) float f32x4;

__device__ __forceinline__ unsigned short rne_bf16(float f) {
  unsigned u = __float_as_uint(f);
  return (unsigned short)((u + 0x7FFFu + ((u >> 16) & 1u)) >> 16);
}
__device__ __forceinline__ float bf2f(unsigned short b) {
  return __uint_as_float(((unsigned)b) << 16);
}

// ---------------- fused x->bf16 + weight prep + deg/bcur zeroing ----------------
__global__ __launch_bounds__(256) void k_cvtprep(const float* __restrict__ x, unsigned short* __restrict__ xb,
                                                 int n8, int N,
                                                 const float* __restrict__ Wl1, const float* __restrict__ Wr1,
                                                 const float* __restrict__ Wl2, const float* __restrict__ Wr2,
                                                 const float* __restrict__ Wl3, const float* __restrict__ Wr3,
                                                 unsigned short* __restrict__ WT1l, unsigned short* __restrict__ WT1r,
                                                 unsigned short* __restrict__ WT2l, unsigned short* __restrict__ WT2r,
                                                 unsigned short* __restrict__ wc3b,
                                                 int* __restrict__ deg, int* __restrict__ bcur) {
  int idx = blockIdx.x * 256 + threadIdx.x;
  if (idx < n8) {
    const float4* p = (const float4*)(x + (size_t)idx * 8);
    float4 v0 = p[0], v1 = p[1];
    ushort8 o;
    o[0] = rne_bf16(v0.x); o[1] = rne_bf16(v0.y); o[2] = rne_bf16(v0.z); o[3] = rne_bf16(v0.w);
    o[4] = rne_bf16(v1.x); o[5] = rne_bf16(v1.y); o[6] = rne_bf16(v1.z); o[7] = rne_bf16(v1.w);
    *(ushort8*)(xb + (size_t)idx * 8) = o;
    return;
  }
  int j = idx - n8;
  if (j < 32768) {
    int k = j >> 8, m = j & 255;
    WT1l[m * 128 + k] = rne_bf16(Wl1[j]);
    WT1r[m * 128 + k] = rne_bf16(Wr1[j]);
  } else if (j < 65536) {
    int q = j - 32768;
    int k = q >> 7, m = q & 127;
    WT2l[m * 256 + k] = rne_bf16(Wl2[q]);
    WT2r[m * 256 + k] = rne_bf16(Wr2[q]);
  } else if (j < 69632) {
    int q = j - 65536;            // q = m*128 + k
    int m = q >> 7, k = q & 127;
    float v = (m < 16) ? Wl3[k * 16 + m] : Wr3[k * 16 + (m - 16)];
    wc3b[q] = rne_bf16(v);
  } else if (j < 69632 + N) {
    deg[j - 69632] = 0;
  } else if (j < 69632 + N + NXCD) {
    bcur[j - 69632 - N] = 0;
  }
}

// ---------------- bucket pass: deg atomics + dst-slice partition ----------------
__global__ __launch_bounds__(256) void k_bucket(const int* __restrict__ src, const int* __restrict__ dst,
                                                int* __restrict__ deg, int* __restrict__ bcur,
                                                int2* __restrict__ bucket, int E, int binsz) {
  __shared__ int cnt[NXCD];
  __shared__ int base[NXCD];
  const int tid = threadIdx.x;
  if (tid < NXCD) cnt[tid] = 0;
  __syncthreads();
  int e0 = (blockIdx.x * 256 + tid) * 4;
  int d[4], s[4], bk[4], rk[4];
  int nv = 0;
  if (e0 + 3 < E) {
    int4 d4 = *(const int4*)(dst + e0);
    int4 s4 = *(const int4*)(src + e0);
    d[0] = d4.x; d[1] = d4.y; d[2] = d4.z; d[3] = d4.w;
    s[0] = s4.x; s[1] = s4.y; s[2] = s4.z; s[3] = s4.w;
    nv = 4;
  } else {
    for (int e = e0; e < E && nv < 4; ++e) { d[nv] = dst[e]; s[nv] = src[e]; ++nv; }
  }
#pragma unroll
  for (int k = 0; k < 4; ++k)
    if (k < nv) {
      atomicAdd(&deg[d[k]], 1);
      bk[k] = d[k] / binsz;
      rk[k] = atomicAdd(&cnt[bk[k]], 1);
    }
  __syncthreads();
  if (tid < NXCD) base[tid] = atomicAdd(&bcur[tid], cnt[tid]);
  __syncthreads();
#pragma unroll
  for (int k = 0; k < 4; ++k)
    if (k < nv) {
      int p = min(base[bk[k]] + rk[k], BCAP - 1);
      bucket[(size_t)bk[k] * BCAP + p] = make_int2(s[k], d[k]);
    }
}

// ---------------- 3-phase parallel scan ----------------
__global__ __launch_bounds__(256) void k_scan_a(const int* __restrict__ deg, int* __restrict__ off,
                                                int* __restrict__ bsum, int N) {
  __shared__ int ws[256];
  const int tid = threadIdx.x;
  const int base = blockIdx.x * 1024 + tid * 4;
  int v0 = (base + 0 < N) ? deg[base + 0] : 0;
  int v1 = (base + 1 < N) ? deg[base + 1] : 0;
  int v2 = (base + 2 < N) ? deg[base + 2] : 0;
  int v3 = (base + 3 < N) ? deg[base + 3] : 0;
  int s = v0 + v1 + v2 + v3;
  ws[tid] = s;
  __syncthreads();
  for (int d = 1; d < 256; d <<= 1) {
    int t = (tid >= d) ? ws[tid - d] : 0;
    __syncthreads();
    ws[tid] += t;
    __syncthreads();
  }
  int excl = ws[tid] - s;
  if (tid == 255) bsum[blockIdx.x] = ws[255];
  if (base + 0 < N) off[base + 0] = excl;
  if (base + 1 < N) off[base + 1] = excl + v0;
  if (base + 2 < N) off[base + 2] = excl + v0 + v1;
  if (base + 3 < N) off[base + 3] = excl + v0 + v1 + v2;
}

__global__ __launch_bounds__(64) void k_scan_b(int* __restrict__ bsum, int nb) {
  int tid = threadIdx.x;
  int v = (tid < nb) ? bsum[tid] : 0;
  for (int d = 1; d < 64; d <<= 1) {
    int t = __shfl_up(v, d, 64);
    if (tid >= d) v += t;
  }
  if (tid < nb) bsum[tid] = v;
}

__global__ __launch_bounds__(256) void k_scan_c(int* __restrict__ off, int* __restrict__ cur,
                                                const int* __restrict__ bsum, int N, int nb) {
  int i = blockIdx.x * 256 + threadIdx.x;
  if (i < N) {
    int b = i >> 10;
    int v = off[i] + ((b > 0) ? bsum[b - 1] : 0);
    off[i] = v;
    cur[i] = v;
  }
  if (i == 0) off[N] = bsum[nb - 1];
}

// ---------------- per-XCD fill from own bucket (L2-local stores) ----------------
__global__ __launch_bounds__(256) void k_fill2(const int2* __restrict__ bucket, const int* __restrict__ bcnt,
                                               const int* __restrict__ off, int* __restrict__ cur,
                                               int* __restrict__ eidx, int N, int binsz, int ngrp) {
  const int xcd = blockIdx.x & (NXCD - 1);
  const int grp = blockIdx.x >> 3;
  const int t = grp * 256 + threadIdx.x;
  const int nthr = ngrp * 256;
  const int lo = xcd * binsz;
  const int hi = min(lo + binsz, N);

  int s0 = off[lo] & ~15;
  int s1 = off[hi];
  for (int i = s0 + t * 16; i < s1; i += nthr * 16) {
    int v = eidx[i];
    asm volatile("" :: "v"(v));
  }

  const int cnt = min(bcnt[xcd], BCAP);
  const int2* seg = bucket + (size_t)xcd * BCAP;
  for (int e = t; e < cnt; e += nthr) {
    int2 sd = seg[e];
    int p = atomicAdd(&cur[sd.y], 1);
    eidx[p] = sd.x;
  }
}

// ---------------- gather-mean, bf16 input (D=128), bf16 out, 4-way unrolled ----------------
__global__ __launch_bounds__(256) void k_aggr_b(const unsigned short* __restrict__ feat,
                                                const int* __restrict__ off, const int* __restrict__ eidx,
                                                unsigned short* __restrict__ out, int N) {
  int idx = blockIdx.x * 256 + threadIdx.x;
  int n = idx >> 4;
  if (n >= N) return;
  int c = (idx & 15) * 8;
  int b = off[n], e = off[n + 1];
  float s0 = 0.f, s1 = 0.f, s2 = 0.f, s3 = 0.f, s4 = 0.f, s5 = 0.f, s6 = 0.f, s7 = 0.f;
  int j = b;
  for (; j + 3 < e; j += 4) {
    int i0 = eidx[j], i1 = eidx[j + 1], i2 = eidx[j + 2], i3 = eidx[j + 3];
    ushort8 v0 = *(const ushort8*)&feat[(size_t)i0 * 128 + c];
    ushort8 v1 = *(const ushort8*)&feat[(size_t)i1 * 128 + c];
    ushort8 v2 = *(const ushort8*)&feat[(size_t)i2 * 128 + c];
    ushort8 v3 = *(const ushort8*)&feat[(size_t)i3 * 128 + c];
    s0 += bf2f(v0[0]) + bf2f(v1[0]) + bf2f(v2[0]) + bf2f(v3[0]);
    s1 += bf2f(v0[1]) + bf2f(v1[1]) + bf2f(v2[1]) + bf2f(v3[1]);
    s2 += bf2f(v0[2]) + bf2f(v1[2]) + bf2f(v2[2]) + bf2f(v3[2]);
    s3 += bf2f(v0[3]) + bf2f(v1[3]) + bf2f(v2[3]) + bf2f(v3[3]);
    s4 += bf2f(v0[4]) + bf2f(v1[4]) + bf2f(v2[4]) + bf2f(v3[4]);
    s5 += bf2f(v0[5]) + bf2f(v1[5]) + bf2f(v2[5]) + bf2f(v3[5]);
    s6 += bf2f(v0[6]) + bf2f(v1[6]) + bf2f(v2[6]) + bf2f(v3[6]);
    s7 += bf2f(v0[7]) + bf2f(v1[7]) + bf2f(v2[7]) + bf2f(v3[7]);
  }
  for (; j < e; ++j) {
    int sidx = eidx[j];
    ushort8 v = *(const ushort8*)&feat[(size_t)sidx * 128 + c];
    s0 += bf2f(v[0]); s1 += bf2f(v[1]); s2 += bf2f(v[2]); s3 += bf2f(v[3]);
    s4 += bf2f(v[4]); s5 += bf2f(v[5]); s6 += bf2f(v[6]); s7 += bf2f(v[7]);
  }
  float sc = 1.f / fmaxf((float)(e - b), 1.f);
  ushort8 o;
  o[0] = rne_bf16(s0 * sc); o[1] = rne_bf16(s1 * sc); o[2] = rne_bf16(s2 * sc); o[3] = rne_bf16(s3 * sc);
  o[4] = rne_bf16(s4 * sc); o[5] = rne_bf16(s5 * sc); o[6] = rne_bf16(s6 * sc); o[7] = rne_bf16(s7 * sc);
  *(ushort8*)&out[(size_t)n * 128 + c] = o;
}

// ---------------- bf16 MFMA GEMM 64x64 tile; C0 (residual) read as bf16 ----------------
template <int DUAL, int HAS_C0, int HAS_BIAS, int RELU, int OUT_BF16>
__global__ __launch_bounds__(256) void k_mgemm(
    const unsigned short* __restrict__ A1, int K1, const unsigned short* __restrict__ B1,
    const unsigned short* __restrict__ A2, const unsigned short* __restrict__ B2, int K2,
    const unsigned short* __restrict__ C0, const float* __restrict__ bias,
    void* __restrict__ Cout, int N, int M) {
  __shared__ unsigned short As[64 * 32];
  __shared__ unsigned short Bs[64 * 32];
  const int tid = threadIdx.x;
  const int row0 = blockIdx.y * 64;
  const int col0 = blockIdx.x * 64;
  const int lane = tid & 63;
  const int w = tid >> 6;
  const int wr = w >> 1, wc = w & 1;
  const int rl = lane & 15, g = lane >> 4;
  const int pos = ((g ^ ((rl >> 1) & 3)) << 3);
  const int srow = tid >> 2;
  const int schunk = tid & 3;
  const int spos = ((schunk ^ ((srow >> 1) & 3)) << 3);

  f32x4 acc00 = {0.f, 0.f, 0.f, 0.f}, acc01 = acc00, acc10 = acc00, acc11 = acc00;

  for (int pass = 0; pass < (DUAL ? 2 : 1); ++pass) {
    const unsigned short* __restrict__ A = pass ? A2 : A1;
    const unsigned short* __restrict__ B = pass ? B2 : B1;
    const int K = pass ? K2 : K1;
    for (int k0 = 0; k0 < K; k0 += 32) {
      {
        int r = row0 + srow;
        ushort8 va = (ushort8)(0);
        if (r < N) va = *(const ushort8*)&A[(size_t)r * K + k0 + schunk * 8];
        *(ushort8*)&As[srow * 32 + spos] = va;
        ushort8 vb = *(const ushort8*)&B[(size_t)(col0 + srow) * K + k0 + schunk * 8];
        *(ushort8*)&Bs[srow * 32 + spos] = vb;
      }
      __syncthreads();
      bf16s8 a0 = *(bf16s8*)&As[(wr * 32 + rl) * 32 + pos];
      bf16s8 a1 = *(bf16s8*)&As[(wr * 32 + 16 + rl) * 32 + pos];
      bf16s8 b0 = *(bf16s8*)&Bs[(wc * 32 + rl) * 32 + pos];
      bf16s8 b1 = *(bf16s8*)&Bs[(wc * 32 + 16 + rl) * 32 + pos];
      acc00 = __builtin_amdgcn_mfma_f32_16x16x32_bf16(a0, b0, acc00, 0, 0, 0);
      acc01 = __builtin_amdgcn_mfma_f32_16x16x32_bf16(a0, b1, acc01, 0, 0, 0);
      acc10 = __builtin_amdgcn_mfma_f32_16x16x32_bf16(a1, b0, acc10, 0, 0, 0);
      acc11 = __builtin_amdgcn_mfma_f32_16x16x32_bf16(a1, b1, acc11, 0, 0, 0);
      __syncthreads();
    }
  }

#pragma unroll
  for (int fi = 0; fi < 2; ++fi)
#pragma unroll
    for (int fj = 0; fj < 2; ++fj) {
      const f32x4 a = fi ? (fj ? acc11 : acc10) : (fj ? acc01 : acc00);
#pragma unroll
      for (int reg = 0; reg < 4; ++reg) {
        int r = row0 + wr * 32 + fi * 16 + g * 4 + reg;
        int c = col0 + wc * 32 + fj * 16 + rl;
        if (r >= N) continue;
        float v = a[reg];
        if (HAS_C0) v += bf2f(C0[(size_t)r * M + c]);
        if (HAS_BIAS) v += bias[c];
        if (RELU) v = fmaxf(v, 0.f);
        if (OUT_BF16) ((unsigned short*)Cout)[(size_t)r * M + c] = rne_bf16(v);
        else ((float*)Cout)[(size_t)r * M + c] = v;
      }
    }
}

// ---------------- layer-3 MFMA GEMM: 128x32 tile, K=128 ----------------
__global__ __launch_bounds__(256) void k_mgemm3(const unsigned short* __restrict__ A,
                                                const unsigned short* __restrict__ B,
                                                float* __restrict__ C, int N) {
  __shared__ unsigned short As[128 * 32];
  __shared__ unsigned short Bs[32 * 32];
  const int tid = threadIdx.x;
  const int row0 = blockIdx.x * 128;
  const int lane = tid & 63;
  const int w = tid >> 6;
  const int rl = lane & 15, g = lane >> 4;
  const int pos = ((g ^ ((rl >> 1) & 3)) << 3);

  f32x4 acc00 = {0.f, 0.f, 0.f, 0.f}, acc01 = acc00, acc10 = acc00, acc11 = acc00;

  for (int k0 = 0; k0 < 128; k0 += 32) {
#pragma unroll
    for (int it = 0; it < 2; ++it) {
      int cid = tid + it * 256;
      int row = cid >> 2, ch = cid & 3;
      int r = row0 + row;
      ushort8 va = (ushort8)(0);
      if (r < N) va = *(const ushort8*)&A[(size_t)r * 128 + k0 + ch * 8];
      *(ushort8*)&As[row * 32 + ((ch ^ ((row >> 1) & 3)) << 3)] = va;
    }
    if (tid < 128) {
      int row = tid >> 2, ch = tid & 3;
      ushort8 vb = *(const ushort8*)&B[(size_t)row * 128 + k0 + ch * 8];
      *(ushort8*)&Bs[row * 32 + ((ch ^ ((row >> 1) & 3)) << 3)] = vb;
    }
    __syncthreads();
    bf16s8 a0 = *(bf16s8*)&As[(w * 32 + rl) * 32 + pos];
    bf16s8 a1 = *(bf16s8*)&As[(w * 32 + 16 + rl) * 32 + pos];
    bf16s8 b0 = *(bf16s8*)&Bs[rl * 32 + pos];
    bf16s8 b1 = *(bf16s8*)&Bs[(16 + rl) * 32 + pos];
    acc00 = __builtin_amdgcn_mfma_f32_16x16x32_bf16(a0, b0, acc00, 0, 0, 0);
    acc01 = __builtin_amdgcn_mfma_f32_16x16x32_bf16(a0, b1, acc01, 0, 0, 0);
    acc10 = __builtin_amdgcn_mfma_f32_16x16x32_bf16(a1, b0, acc10, 0, 0, 0);
    acc11 = __builtin_amdgcn_mfma_f32_16x16x32_bf16(a1, b1, acc11, 0, 0, 0);
    __syncthreads();
  }

#pragma unroll
  for (int fi = 0; fi < 2; ++fi)
#pragma unroll
    for (int fj = 0; fj < 2; ++fj) {
      const f32x4 a = fi ? (fj ? acc11 : acc10) : (fj ? acc01 : acc00);
#pragma unroll
      for (int reg = 0; reg < 4; ++reg) {
        int r = row0 + w * 32 + fi * 16 + g * 4 + reg;
        int c = fj * 16 + rl;
        if (r < N) C[(size_t)r * 32 + c] = a[reg];
      }
    }
}

// ---------------- fused layer-3 aggregate + combine (4-way unrolled) ----------------
__global__ __launch_bounds__(256) void k_l3post(const float* __restrict__ g3, const int* __restrict__ off,
                                                const int* __restrict__ eidx, const float* __restrict__ bl3,
                                                float* __restrict__ h3, int N) {
  int idx = blockIdx.x * 256 + threadIdx.x;
  int n = idx >> 2;
  if (n >= N) return;
  int c = (idx & 3) << 2;
  int b = off[n], e = off[n + 1];
  float ax = 0.f, ay = 0.f, az = 0.f, aw = 0.f;
  int j = b;
  for (; j + 3 < e; j += 4) {
    int i0 = eidx[j], i1 = eidx[j + 1], i2 = eidx[j + 2], i3 = eidx[j + 3];
    const float4 v0 = *(const float4*)&g3[(size_t)i0 * 32 + c];
    const float4 v1 = *(const float4*)&g3[(size_t)i1 * 32 + c];
    const float4 v2 = *(const float4*)&g3[(size_t)i2 * 32 + c];
    const float4 v3 = *(const float4*)&g3[(size_t)i3 * 32 + c];
    ax += v0.x + v1.x + v2.x + v3.x;
    ay += v0.y + v1.y + v2.y + v3.y;
    az += v0.z + v1.z + v2.z + v3.z;
    aw += v0.w + v1.w + v2.w + v3.w;
  }
  for (; j < e; ++j) {
    int s = eidx[j];
    const float4 v = *(const float4*)&g3[(size_t)s * 32 + c];
    ax += v.x; ay += v.y; az += v.z; aw += v.w;
  }
  float sc = 1.f / fmaxf((float)(e - b), 1.f);
  const float4 r2 = *(const float4*)&g3[(size_t)n * 32 + 16 + c];
  const float4 bb = *(const float4*)&bl3[c];
  *(float4*)&h3[(size_t)n * 16 + c] =
      make_float4(ax * sc + r2.x + bb.x, ay * sc + r2.y + bb.y,
                  az * sc + r2.z + bb.z, aw * sc + r2.w + bb.w);
}

// ---------------- threefry2x32 ----------------
__device__ __forceinline__ uint2 tf2x32(unsigned k0, unsigned k1, unsigned x0, unsigned x1) {
  const unsigned ks[3] = {k0, k1, k0 ^ k1 ^ 0x1BD11BDAu};
  const int rotA[4] = {13, 15, 26, 6}, rotB[4] = {17, 29, 16, 24};
  x0 += ks[0];
  x1 += ks[1];
#pragma unroll
  for (int i = 0; i < 5; ++i) {
    const int* R = (i & 1) ? rotB : rotA;
#pragma unroll
    for (int j = 0; j < 4; ++j) {
      x0 += x1;
      x1 = (x1 << R[j]) | (x1 >> (32 - R[j]));
      x1 ^= x0;
    }
    x0 += ks[(i + 1) % 3];
    x1 += ks[(i + 2) % 3] + (unsigned)(i + 1);
  }
  return make_uint2(x0, x1);
}

// ---------------- global mean pool + dropout + final linear (fused) ----------------
__device__ __forceinline__ int lbound(const int* __restrict__ a, int n, int v) {
  int lo = 0, hi = n;
  while (lo < hi) {
    int mid = (lo + hi) >> 1;
    if (a[mid] < v) lo = mid + 1; else hi = mid;
  }
  return lo;
}

__global__ __launch_bounds__(256) void k_poolfinal(const float* __restrict__ h3, const int* __restrict__ batch,
                                                   int N, const float* __restrict__ Wc,
                                                   const float* __restrict__ bc, float* __restrict__ outp) {
  __shared__ float sm[4][16];
  int g = blockIdx.x, tid = threadIdx.x;
  int start = lbound(batch, N, g);
  int end = lbound(batch, N, g + 1);
  float acc[16];
#pragma unroll
  for (int j = 0; j < 16; ++j) acc[j] = 0.f;
  for (int i = start + tid; i < end; i += 256) {
    const float4* p = (const float4*)&h3[(size_t)i * 16];
    float4 v0 = p[0], v1 = p[1], v2 = p[2], v3 = p[3];
    acc[0] += v0.x; acc[1] += v0.y; acc[2] += v0.z; acc[3] += v0.w;
    acc[4] += v1.x; acc[5] += v1.y; acc[6] += v1.z; acc[7] += v1.w;
    acc[8] += v2.x; acc[9] += v2.y; acc[10] += v2.z; acc[11] += v2.w;
    acc[12] += v3.x; acc[13] += v3.y; acc[14] += v3.z; acc[15] += v3.w;
  }
#pragma unroll
  for (int j = 0; j < 16; ++j) {
    float v = acc[j];
    v += __shfl_down(v, 32);
    v += __shfl_down(v, 16);
    v += __shfl_down(v, 8);
    v += __shfl_down(v, 4);
    v += __shfl_down(v, 2);
    v += __shfl_down(v, 1);
    if ((tid & 63) == 0) sm[tid >> 6][j] = v;
  }
  __syncthreads();
  if (tid < 16) {
    float v = sm[0][tid] + sm[1][tid] + sm[2][tid] + sm[3][tid];
    v /= fmaxf((float)(end - start), 1.f);
    outp[64 + g * 16 + tid] = v;                       // output 1 (h_pool)
    uint2 r = tf2x32(0u, 42u, 0u, (unsigned)(g * 16 + tid));
    unsigned bits = r.x ^ r.y;
    float hd = (bits >> 31) ? 0.f : 2.f * v;
    float contrib = hd * Wc[tid];
    contrib += __shfl_down(contrib, 8, 16);
    contrib += __shfl_down(contrib, 4, 16);
    contrib += __shfl_down(contrib, 2, 16);
    contrib += __shfl_down(contrib, 1, 16);
    if (tid == 0) outp[g] = contrib + bc[0];           // output 0
  }
}

extern "C" void kernel_launch(void* const* d_in, const int* in_sizes, int n_in,
                              void* d_out, int out_size, void* d_ws, size_t ws_size,
                              hipStream_t stream) {
  const float* x   = (const float*)d_in[0];
  const int*   ei  = (const int*)d_in[1];
  const int*   bat = (const int*)d_in[2];
  const float* Wl1 = (const float*)d_in[3];
  const float* bl1 = (const float*)d_in[4];
  const float* Wr1 = (const float*)d_in[5];
  const float* Wl2 = (const float*)d_in[6];
  const float* bl2 = (const float*)d_in[7];
  const float* Wr2 = (const float*)d_in[8];
  const float* Wl3 = (const float*)d_in[9];
  const float* bl3 = (const float*)d_in[10];
  const float* Wr3 = (const float*)d_in[11];
  const float* Wc  = (const float*)d_in[12];
  const float* bc  = (const float*)d_in[13];

  const int E = in_sizes[1] / 2;   // 800000
  const int N = in_sizes[2];       // 50000
  const int* src = ei;
  const int* dst = ei + E;

  // workspace layout (4-byte words)
  int*   off   = (int*)d_ws;                          // [0, 50016)
  int*   deg   = off + 50016;                         // [50016, 100016)
  int*   bsum  = (int*)d_ws + 100016;                 // 64
  int*   bcur  = (int*)d_ws + 100080;                 // 8
  unsigned short* wc3b = (unsigned short*)((float*)d_ws + 101120);  // 32x128 bf16
  unsigned short* WT1l = (unsigned short*)((float*)d_ws + 105216);  // 256x128 bf16
  unsigned short* WT1r = (unsigned short*)((float*)d_ws + 121600);
  unsigned short* WT2l = (unsigned short*)((float*)d_ws + 137984);  // 128x256 bf16
  unsigned short* WT2r = (unsigned short*)((float*)d_ws + 154368);
  int*   eidx  = (int*)d_ws + 170752;                 // E
  unsigned short* xb   = (unsigned short*)((float*)d_ws + 970752);    // N*128 bf16
  unsigned short* aggb = (unsigned short*)((float*)d_ws + 4170752);   // N*128 bf16 (agg1 & agg2)
  unsigned short* h1b  = (unsigned short*)((float*)d_ws + 7370752);   // N*256 bf16
  unsigned short* t2b  = xb;                                          // alias (xb dead)
  unsigned short* h2b  = (unsigned short*)((float*)d_ws + 970752);    // N*128 bf16 (t2b dead)
  int*   cur  = (int*)((float*)d_ws + 13770752);      // N cursor
  int2*  bucket = (int2*)((float*)d_ws + 13820800);   // 8*BCAP int2
  float* g3   = (float*)d_ws + 7370752;               // N*32 f32 (h1b dead)
  float* h3   = (float*)d_ws + 8970752;               // N*16 f32
  float* outp = (float*)d_out;                        // 1088 f32

  const int gy = (N + 63) / 64;                       // 782
  const int gy3 = (N + 127) / 128;                    // 391
  const int nb = (N + 1023) / 1024;                   // 49
  const int n8 = N * 128 / 8;                         // 800000
  const int binsz = (N + NXCD - 1) / NXCD;            // 6250
  const int ngrp = 64;

  // prep: x->bf16 + weights + deg/bcur zeroing
  const int prep_total = n8 + 69632 + N + NXCD;
  k_cvtprep<<<(prep_total + 255) / 256, 256, 0, stream>>>(x, xb, n8, N, Wl1, Wr1, Wl2, Wr2, Wl3, Wr3,
                                                          WT1l, WT1r, WT2l, WT2r, wc3b, deg, bcur);

  // CSR build: bucket -> 3-phase scan -> fill2
  k_bucket<<<((E + 3) / 4 + 255) / 256, 256, 0, stream>>>(src, dst, deg, bcur, bucket, E, binsz);
  k_scan_a<<<nb, 256, 0, stream>>>(deg, off, bsum, N);
  k_scan_b<<<1, 64, 0, stream>>>(bsum, nb);
  k_scan_c<<<(N + 255) / 256, 256, 0, stream>>>(off, cur, bsum, N, nb);
  k_fill2<<<ngrp * NXCD, 256, 0, stream>>>(bucket, bcur, off, cur, eidx, N, binsz, ngrp);

  // layer 1
  k_aggr_b<<<(N * 16 + 255) / 256, 256, 0, stream>>>(xb, off, eidx, aggb, N);
  k_mgemm<1, 0, 1, 1, 1><<<dim3(4, gy), 256, 0, stream>>>(aggb, 128, WT1l, xb, WT1r, 128,
                                                          nullptr, bl1, h1b, N, 256);

  // layer 2 (agg2 reuses aggb region, bf16)
  k_mgemm<0, 0, 0, 0, 1><<<dim3(2, gy), 256, 0, stream>>>(h1b, 256, WT2l, nullptr, nullptr, 0,
                                                          nullptr, nullptr, t2b, N, 128);
  k_aggr_b<<<(N * 16 + 255) / 256, 256, 0, stream>>>(t2b, off, eidx, aggb, N);
  k_mgemm<0, 1, 1, 1, 1><<<dim3(2, gy), 256, 0, stream>>>(h1b, 256, WT2r, nullptr, nullptr, 0,
                                                          aggb, bl2, h2b, N, 128);

  // layer 3
  k_mgemm3<<<gy3, 256, 0, stream>>>(h2b, wc3b, g3, N);
  k_l3post<<<(N * 4 + 255) / 256, 256, 0, stream>>>(g3, off, eidx, bl3, h3, N);

  // pool + dropout + final linear (fused)
  k_poolfinal<<<GG, 256, 0, stream>>>(h3, bat, N, Wc, bc, outp);
}